// Round 12
// baseline (864.257 us; speedup 1.0000x reference)
//
#include <hip/hip_runtime.h>
#include <stdint.h>

#define NN 100000   // nodes
#define NE 400000   // edges per relation
#define NR 3        // relations
#define NF 256      // feature dim
#define NK 768      // NR*NF concatenated K
#define NG 128      // graphs
#define SCAN_NB ((NN + 1023) / 1024)   // 98 chunks of 1024

typedef __attribute__((ext_vector_type(4))) unsigned short ushortx4;
typedef __attribute__((ext_vector_type(8))) unsigned short ushortx8;
typedef __attribute__((ext_vector_type(8))) short short8;
typedef __attribute__((ext_vector_type(4))) float floatx4;

static __device__ __forceinline__ unsigned short f2bfu(float f) {
  union { float f; uint32_t u; } c; c.f = f;
  uint32_t x = c.u;
  uint32_t r = (x + 0x7fffu + ((x >> 16) & 1u)) >> 16;
  return (unsigned short)r;
}
static __device__ __forceinline__ float bfu2f(unsigned short u) {
  union { uint32_t u; float f; } c; c.u = ((uint32_t)u) << 16;
  return c.f;
}

// ---------------- graph preprocessing ----------------

__global__ __launch_bounds__(256) void degree_kernel(
    const int* __restrict__ src, const int* __restrict__ dst,
    int* __restrict__ deg_out, int* __restrict__ deg_in) {
  int t = blockIdx.x * 256 + threadIdx.x;
  int r = blockIdx.y;
  if (t < NE) {
    atomicAdd(&deg_out[r * NN + src[r * NE + t]], 1);
    atomicAdd(&deg_in[r * NN + dst[r * NE + t]], 1);
  }
}

// gid is sorted: count[g] = lb(g+1) - lb(g) via binary search. No atomics.
__global__ __launch_bounds__(128) void gcount_kernel(
    const int* __restrict__ gid, int* __restrict__ gcount) {
  int g = threadIdx.x;  // 0..127
  int lo = 0, hi = NN;
  while (lo < hi) { int mid = (lo + hi) >> 1; if (gid[mid] < g) lo = mid + 1; else hi = mid; }
  int a = lo;
  lo = 0; hi = NN;
  while (lo < hi) { int mid = (lo + hi) >> 1; if (gid[mid] < g + 1) lo = mid + 1; else hi = mid; }
  gcount[g] = lo - a;
}

__global__ __launch_bounds__(256) void norm_kernel(
    const int* __restrict__ deg_out, const int* __restrict__ deg_in,
    float* __restrict__ n_src, float* __restrict__ n_dst) {
  int t = blockIdx.x * 256 + threadIdx.x;
  if (t < NR * NN) {
    int dof = deg_out[t], din = deg_in[t];
    n_src[t] = dof > 0 ? rsqrtf((float)dof) : 0.f;
    n_dst[t] = din > 0 ? rsqrtf((float)din) : 0.f;
  }
}

// ---- multi-block exclusive scan of deg_in -> rowptr (3 phases) ----

__global__ __launch_bounds__(256) void scan_phaseA(
    const int* __restrict__ deg_in, int* __restrict__ blocksum) {
  int r = blockIdx.y, b = blockIdx.x, tid = threadIdx.x;
  const int* deg = deg_in + (size_t)r * NN;
  int base = b * 1024 + tid * 4;
  int s = 0;
#pragma unroll
  for (int i = 0; i < 4; ++i) { int idx = base + i; if (idx < NN) s += deg[idx]; }
  __shared__ int red[256];
  red[tid] = s; __syncthreads();
  for (int off = 128; off > 0; off >>= 1) {
    if (tid < off) red[tid] += red[tid + off];
    __syncthreads();
  }
  if (tid == 0) blocksum[r * SCAN_NB + b] = red[0];
}

__global__ __launch_bounds__(128) void scan_phaseB(
    int* __restrict__ blocksum, int* __restrict__ rowptr) {
  int r = blockIdx.x, tid = threadIdx.x;
  int* bs = blocksum + r * SCAN_NB;
  __shared__ int buf[128];
  int v = (tid < SCAN_NB) ? bs[tid] : 0;
  buf[tid] = v; __syncthreads();
  for (int off = 1; off < 128; off <<= 1) {
    int t = (tid >= off) ? buf[tid - off] : 0;
    __syncthreads();
    buf[tid] += t;
    __syncthreads();
  }
  if (tid < SCAN_NB) bs[tid] = buf[tid] - v;   // exclusive chunk offset
  if (tid == 127) rowptr[(size_t)r * (NN + 1) + NN] = buf[127];
}

__global__ __launch_bounds__(256) void scan_phaseC(
    const int* __restrict__ deg_in, const int* __restrict__ blocksum,
    int* __restrict__ rowptr) {
  int r = blockIdx.y, b = blockIdx.x, tid = threadIdx.x;
  const int* deg = deg_in + (size_t)r * NN;
  int* rp = rowptr + (size_t)r * (NN + 1);
  int base = b * 1024 + tid * 4;
  int v[4]; int s = 0;
#pragma unroll
  for (int i = 0; i < 4; ++i) { int idx = base + i; v[i] = (idx < NN) ? deg[idx] : 0; s += v[i]; }
  __shared__ int buf[256];
  buf[tid] = s; __syncthreads();
  for (int off = 1; off < 256; off <<= 1) {
    int t = (tid >= off) ? buf[tid - off] : 0;
    __syncthreads();
    buf[tid] += t;
    __syncthreads();
  }
  int excl = buf[tid] - s + blocksum[r * SCAN_NB + b];
#pragma unroll
  for (int i = 0; i < 4; ++i) {
    int idx = base + i;
    if (idx < NN) rp[idx] = excl;
    excl += v[i];
  }
}

// cursor is a COPY of rowptr (layout [r][NN+1]); atomicAdd gives the absolute
// CSR slot directly -> no random rowptr load per edge.
__global__ __launch_bounds__(256) void scatter_kernel(
    const int* __restrict__ src, const int* __restrict__ dst,
    int* __restrict__ cursor, const float* __restrict__ n_src,
    int2* __restrict__ csr_e) {
  int t = blockIdx.x * 256 + threadIdx.x;
  int r = blockIdx.y;
  if (t < NE) {
    int s = src[r * NE + t], v = dst[r * NE + t];
    int pos = atomicAdd(&cursor[r * (NN + 1) + v], 1);   // absolute within relation
    csr_e[(size_t)r * NE + pos] = make_int2(s, __float_as_int(n_src[r * NN + s]));
  }
}

// ---------------- weight / feature prep ----------------

// Tiled LDS transpose: W[lay][r][k][n] (f32) -> wt[lay][n][r*256+k] (bf16).
__global__ __launch_bounds__(256) void prep_w_kernel(
    const float* __restrict__ W1, const float* __restrict__ W2,
    unsigned short* __restrict__ wt1, unsigned short* __restrict__ wt2) {
  __shared__ float lds[64][65];
  const int tile = blockIdx.x;          // 0..15: (kt,nt) 4x4
  const int r = blockIdx.y;             // 0..2
  const int lay = blockIdx.z;           // 0..1
  const float* W = lay ? W2 : W1;
  unsigned short* wt = lay ? wt2 : wt1;
  const int k0 = (tile >> 2) * 64, n0 = (tile & 3) * 64;
  const int ty = threadIdx.x >> 6;      // 0..3
  const int tx = threadIdx.x & 63;      // 0..63

#pragma unroll
  for (int i = 0; i < 16; ++i) {
    int kl = ty * 16 + i;               // local k row
    lds[kl][tx] = W[((size_t)r * NF + k0 + kl) * NF + n0 + tx];  // coalesced over tx
  }
  __syncthreads();
#pragma unroll
  for (int i = 0; i < 16; ++i) {
    int nl = ty * 16 + i;               // local n row
    wt[(size_t)(n0 + nl) * NK + r * NF + k0 + tx] = f2bfu(lds[tx][nl]);
  }
}

__global__ __launch_bounds__(256) void prep_bias_kernel(
    const float* __restrict__ b1, const float* __restrict__ b2,
    float* __restrict__ bs1, float* __restrict__ bs2) {
  int t = blockIdx.x * 256 + threadIdx.x;   // 512
  if (t < 2 * NF) {
    int lay = t / NF, n = t % NF;
    const float* b = lay ? b2 : b1;
    float* bs = lay ? bs2 : bs1;
    bs[n] = b[n] + b[NF + n] + b[2 * NF + n];
  }
}

// NT load: feat is read exactly once.
__global__ __launch_bounds__(256) void cast_kernel(
    const float* __restrict__ in, unsigned short* __restrict__ out, int n4) {
  int t = blockIdx.x * 256 + threadIdx.x;
  if (t < n4) {
    floatx4 v = __builtin_nontemporal_load((const floatx4*)&in[(size_t)t * 4]);
    ushortx4 o;
    o.x = f2bfu(v.x); o.y = f2bfu(v.y); o.z = f2bfu(v.z); o.w = f2bfu(v.w);
    *(ushortx4*)&out[(size_t)t * 4] = o;
  }
}

// ---------------- SpMM: one wave per NODE, 3 relations interleaved (R7) ----------------

__global__ __launch_bounds__(256) void spmm_kernel(
    const unsigned short* __restrict__ x,   // [NN][256] bf16
    const int* __restrict__ rowptr, const int2* __restrict__ csr_e,
    const float* __restrict__ n_dst,
    unsigned short* __restrict__ agg) {     // [NN][768] bf16
  int wid = threadIdx.x >> 6, l = threadIdx.x & 63;
  int v = blockIdx.x * 4 + wid;
  if (v >= NN) return;
  const int half = l >> 5;        // 0: edge e, 1: edge e+1
  const int c8 = (l & 31) * 8;    // this lane's 8-col strip

  int ea = rowptr[v],                e1a = rowptr[v + 1];
  int eb = rowptr[(NN + 1) + v],     e1b = rowptr[(NN + 1) + v + 1];
  int ec = rowptr[2 * (NN + 1) + v], e1c = rowptr[2 * (NN + 1) + v + 1];
  const int2* cea = csr_e;
  const int2* ceb = csr_e + (size_t)NE;
  const int2* cec = csr_e + (size_t)2 * NE;

  float a[NR][8];
#pragma unroll
  for (int r = 0; r < NR; ++r)
#pragma unroll
    for (int j = 0; j < 8; ++j) a[r][j] = 0.f;

  while (ea < e1a || eb < e1b || ec < e1c) {
    if (ea < e1a) {
      if (ea + half < e1a) {
        int2 p = cea[ea + half];
        float w = __int_as_float(p.y);
        ushortx8 xv = *(const ushortx8*)&x[(size_t)p.x * NF + c8];
#pragma unroll
        for (int j = 0; j < 8; ++j) a[0][j] += w * bfu2f(xv[j]);
      }
      ea += 2;
    }
    if (eb < e1b) {
      if (eb + half < e1b) {
        int2 p = ceb[eb + half];
        float w = __int_as_float(p.y);
        ushortx8 xv = *(const ushortx8*)&x[(size_t)p.x * NF + c8];
#pragma unroll
        for (int j = 0; j < 8; ++j) a[1][j] += w * bfu2f(xv[j]);
      }
      eb += 2;
    }
    if (ec < e1c) {
      if (ec + half < e1c) {
        int2 p = cec[ec + half];
        float w = __int_as_float(p.y);
        ushortx8 xv = *(const ushortx8*)&x[(size_t)p.x * NF + c8];
#pragma unroll
        for (int j = 0; j < 8; ++j) a[2][j] += w * bfu2f(xv[j]);
      }
      ec += 2;
    }
  }

#pragma unroll
  for (int r = 0; r < NR; ++r)
#pragma unroll
    for (int j = 0; j < 8; ++j) a[r][j] += __shfl_xor(a[r][j], 32);

  if (l < 32) {
#pragma unroll
    for (int r = 0; r < NR; ++r) {
      float nd = n_dst[r * NN + v];
      ushortx8 o;
#pragma unroll
      for (int j = 0; j < 8; ++j) o[j] = f2bfu(a[r][j] * nd);
      *(ushortx8*)&agg[(size_t)v * NK + r * NF + c8] = o;
    }
  }
}

// ---------------- GEMM: LDS-free direct-MFMA stream ----------------
// [M,768] @ [768,256]. No LDS, no barriers: A/B fragments loaded global->VGPR
// in MFMA lane layout. A bytes read once per block (4-wave dup absorbed by L1;
// kt/kt+1 share a 128B line); B (393KB) is L2-resident. Compiler freely
// software-pipelines the 12 loads/K-step under the 32 MFMAs (Guideline 7) --
// removes the 24x (vmcnt(0)+2 barriers) the LDS version paid at K-depth 24.

__global__ __launch_bounds__(256, 2) void gemm_kernel(
    const unsigned short* __restrict__ A,    // [M][768] bf16
    const unsigned short* __restrict__ Bt,   // [256][768] bf16 (B^T: [col][K])
    const float* __restrict__ bias,          // [256]
    unsigned short* __restrict__ C,          // [M][256] bf16
    int M, int relu) {
  const int l = threadIdx.x & 63, wid = threadIdx.x >> 6;
  const int row0 = blockIdx.x * 128;
  const int c0 = wid * 64;                    // wave's 64-col strip
  const int fr = l & 15, fk = (l >> 4) * 8;

  // per-lane fragment base pointers (row clamped; C-write masks tail rows)
  const unsigned short* arow[8];
#pragma unroll
  for (int m = 0; m < 8; ++m) {
    int r = row0 + m * 16 + fr;
    if (r >= M) r = M - 1;
    arow[m] = A + (size_t)r * NK + fk;
  }
  const unsigned short* brow[4];
#pragma unroll
  for (int n = 0; n < 4; ++n)
    brow[n] = Bt + (size_t)(c0 + n * 16 + fr) * NK + fk;

  floatx4 acc[8][4];
#pragma unroll
  for (int m = 0; m < 8; ++m)
#pragma unroll
    for (int n = 0; n < 4; ++n)
#pragma unroll
      for (int q = 0; q < 4; ++q) acc[m][n][q] = 0.f;

#pragma unroll 4
  for (int kt = 0; kt < NK / 32; ++kt) {
    const int ko = kt * 32;
    short8 af[8], bf[4];
#pragma unroll
    for (int m = 0; m < 8; ++m) af[m] = *(const short8*)(arow[m] + ko);
#pragma unroll
    for (int n = 0; n < 4; ++n) bf[n] = *(const short8*)(brow[n] + ko);
#pragma unroll
    for (int m = 0; m < 8; ++m)
#pragma unroll
      for (int n = 0; n < 4; ++n)
        acc[m][n] = __builtin_amdgcn_mfma_f32_16x16x32_bf16(af[m], bf[n], acc[m][n], 0, 0, 0);
  }

  const int fq = l >> 4;
#pragma unroll
  for (int m = 0; m < 8; ++m) {
#pragma unroll
    for (int n = 0; n < 4; ++n) {
      int col = c0 + n * 16 + fr;
      float bv = bias[col];
#pragma unroll
      for (int q = 0; q < 4; ++q) {
        int row = row0 + m * 16 + fq * 4 + q;
        if (row < M) {
          float vv = acc[m][n][q] + bv;
          if (relu) vv = fmaxf(vv, 0.f);
          C[(size_t)row * NF + col] = f2bfu(vv);
        }
      }
    }
  }
}

// ---------------- pooling ----------------

__global__ __launch_bounds__(256) void pool_kernel(
    const unsigned short* __restrict__ h2, const int* __restrict__ gid,
    float* __restrict__ poolsum) {
  int c = threadIdx.x;                 // column 0..255
  int v0 = blockIdx.x * 256;
  int vend = min(v0 + 256, NN);
  float acc = 0.f;
  int curg = -1;
  for (int v = v0; v < vend; ++v) {
    int g = gid[v];                    // sorted -> few runs per chunk
    if (g != curg) {
      if (curg >= 0) atomicAdd(&poolsum[curg * NF + c], acc);
      curg = g; acc = 0.f;
    }
    acc += bfu2f(h2[(size_t)v * NF + c]);
  }
  if (curg >= 0) atomicAdd(&poolsum[curg * NF + c], acc);
}

__global__ __launch_bounds__(256) void final_kernel(
    const float* __restrict__ poolsum, const int* __restrict__ gcount,
    float* __restrict__ out) {
  int g = blockIdx.x, c = threadIdx.x;
  out[g * NF + c] = poolsum[g * NF + c] / fmaxf((float)gcount[g], 1.f);
}

// ---------------- launch ----------------

extern "C" void kernel_launch(void* const* d_in, const int* in_sizes, int n_in,
                              void* d_out, int out_size, void* d_ws, size_t ws_size,
                              hipStream_t stream) {
  const float* feat = (const float*)d_in[0];
  const int* src = (const int*)d_in[1];
  const int* dst = (const int*)d_in[2];
  const int* gid = (const int*)d_in[3];
  const float* W1 = (const float*)d_in[4];
  const float* b1 = (const float*)d_in[5];
  const float* W2 = (const float*)d_in[6];
  const float* b2 = (const float*)d_in[7];
  float* out = (float*)d_out;

  char* ws = (char*)d_ws;
  size_t off = 0;
  auto alloc = [&](size_t bytes) -> void* {
    void* p = ws + off;
    off = (off + bytes + 255) & ~(size_t)255;
    return p;
  };

  // zero-initialized block (single memset)
  int* deg_out = (int*)alloc((size_t)NR * NN * 4);
  int* deg_in  = (int*)alloc((size_t)NR * NN * 4);
  float* poolsum = (float*)alloc((size_t)NG * NF * 4);
  size_t zero_bytes = off;

  int* cursor  = (int*)alloc((size_t)NR * (NN + 1) * 4);
  int* gcount  = (int*)alloc((size_t)NG * 4);
  int* blocksum = (int*)alloc((size_t)NR * SCAN_NB * 4);
  float* n_src = (float*)alloc((size_t)NR * NN * 4);
  float* n_dst = (float*)alloc((size_t)NR * NN * 4);
  int* rowptr  = (int*)alloc((size_t)NR * (NN + 1) * 4);
  int2* csr_e  = (int2*)alloc((size_t)NR * NE * 8);
  unsigned short* wt1 = (unsigned short*)alloc((size_t)NF * NK * 2);
  unsigned short* wt2 = (unsigned short*)alloc((size_t)NF * NK * 2);
  float* bs1 = (float*)alloc(NF * 4);
  float* bs2 = (float*)alloc(NF * 4);
  unsigned short* featbf = (unsigned short*)alloc((size_t)NN * NF * 2);
  unsigned short* h1 = (unsigned short*)alloc((size_t)NN * NF * 2);
  unsigned short* h2 = (unsigned short*)alloc((size_t)NN * NF * 2);
  unsigned short* agg = (unsigned short*)alloc((size_t)NN * NK * 2);
  (void)ws_size; (void)in_sizes; (void)n_in; (void)out_size;

  hipMemsetAsync(d_ws, 0, zero_bytes, stream);

  dim3 eg((NE + 255) / 256, NR);
  degree_kernel<<<eg, 256, 0, stream>>>(src, dst, deg_out, deg_in);
  gcount_kernel<<<1, 128, 0, stream>>>(gid, gcount);
  norm_kernel<<<(NR * NN + 255) / 256, 256, 0, stream>>>(deg_out, deg_in, n_src, n_dst);
  scan_phaseA<<<dim3(SCAN_NB, NR), 256, 0, stream>>>(deg_in, blocksum);
  scan_phaseB<<<NR, 128, 0, stream>>>(blocksum, rowptr);
  scan_phaseC<<<dim3(SCAN_NB, NR), 256, 0, stream>>>(deg_in, blocksum, rowptr);
  hipMemcpyAsync(cursor, rowptr, (size_t)NR * (NN + 1) * 4,
                 hipMemcpyDeviceToDevice, stream);
  scatter_kernel<<<eg, 256, 0, stream>>>(src, dst, cursor, n_src, csr_e);

  prep_w_kernel<<<dim3(16, NR, 2), 256, 0, stream>>>(W1, W2, wt1, wt2);
  prep_bias_kernel<<<2, 256, 0, stream>>>(b1, b2, bs1, bs2);
  cast_kernel<<<(NN * NF / 4 + 255) / 256, 256, 0, stream>>>(feat, featbf, NN * NF / 4);

  // layer 1
  spmm_kernel<<<(NN + 3) / 4, 256, 0, stream>>>(featbf, rowptr, csr_e, n_dst, agg);
  gemm_kernel<<<(NN + 127) / 128, 256, 0, stream>>>(agg, wt1, bs1, h1, NN, 1);
  // layer 2
  spmm_kernel<<<(NN + 3) / 4, 256, 0, stream>>>(h1, rowptr, csr_e, n_dst, agg);
  gemm_kernel<<<(NN + 127) / 128, 256, 0, stream>>>(agg, wt2, bs2, h2, NN, 0);
  // pooling
  pool_kernel<<<(NN + 255) / 256, 256, 0, stream>>>(h2, gid, poolsum);
  final_kernel<<<NG, 256, 0, stream>>>(poolsum, gcount, out);
}

// Round 13
// 723.660 us; speedup vs baseline: 1.1943x; 1.1943x over previous
//
#include <hip/hip_runtime.h>
#include <stdint.h>

#define NN 100000   // nodes
#define NE 400000   // edges per relation
#define NR 3        // relations
#define NF 256      // feature dim
#define NK 768      // NR*NF concatenated K
#define NG 128      // graphs
#define SCAN_NB ((NN + 1023) / 1024)   // 98 chunks of 1024

typedef __attribute__((ext_vector_type(4))) unsigned short ushortx4;
typedef __attribute__((ext_vector_type(8))) unsigned short ushortx8;
typedef __attribute__((ext_vector_type(8))) short short8;
typedef __attribute__((ext_vector_type(4))) float floatx4;

static __device__ __forceinline__ unsigned short f2bfu(float f) {
  union { float f; uint32_t u; } c; c.f = f;
  uint32_t x = c.u;
  uint32_t r = (x + 0x7fffu + ((x >> 16) & 1u)) >> 16;
  return (unsigned short)r;
}
static __device__ __forceinline__ float bfu2f(unsigned short u) {
  union { uint32_t u; float f; } c; c.u = ((uint32_t)u) << 16;
  return c.f;
}

static __device__ __forceinline__ void gload16(const void* g, void* l) {
  __builtin_amdgcn_global_load_lds(
      (const __attribute__((address_space(1))) uint32_t*)g,
      (__attribute__((address_space(3))) uint32_t*)l, 16, 0, 0);
}

// ---------------- graph preprocessing ----------------

__global__ __launch_bounds__(256) void degree_kernel(
    const int* __restrict__ src, const int* __restrict__ dst,
    int* __restrict__ deg_out, int* __restrict__ deg_in) {
  int t = blockIdx.x * 256 + threadIdx.x;
  int r = blockIdx.y;
  if (t < NE) {
    atomicAdd(&deg_out[r * NN + src[r * NE + t]], 1);
    atomicAdd(&deg_in[r * NN + dst[r * NE + t]], 1);
  }
}

// ---- multi-block exclusive scan of deg_in -> rowptr (3 phases) ----

__global__ __launch_bounds__(256) void scan_phaseA(
    const int* __restrict__ deg_in, int* __restrict__ blocksum) {
  int r = blockIdx.y, b = blockIdx.x, tid = threadIdx.x;
  const int* deg = deg_in + (size_t)r * NN;
  int base = b * 1024 + tid * 4;
  int s = 0;
#pragma unroll
  for (int i = 0; i < 4; ++i) { int idx = base + i; if (idx < NN) s += deg[idx]; }
  __shared__ int red[256];
  red[tid] = s; __syncthreads();
  for (int off = 128; off > 0; off >>= 1) {
    if (tid < off) red[tid] += red[tid + off];
    __syncthreads();
  }
  if (tid == 0) blocksum[r * SCAN_NB + b] = red[0];
}

__global__ __launch_bounds__(128) void scan_phaseB(
    int* __restrict__ blocksum, int* __restrict__ rowptr) {
  int r = blockIdx.x, tid = threadIdx.x;
  int* bs = blocksum + r * SCAN_NB;
  __shared__ int buf[128];
  int v = (tid < SCAN_NB) ? bs[tid] : 0;
  buf[tid] = v; __syncthreads();
  for (int off = 1; off < 128; off <<= 1) {
    int t = (tid >= off) ? buf[tid - off] : 0;
    __syncthreads();
    buf[tid] += t;
    __syncthreads();
  }
  if (tid < SCAN_NB) bs[tid] = buf[tid] - v;   // exclusive chunk offset
  if (tid == 127) rowptr[(size_t)r * (NN + 1) + NN] = buf[127];
}

// phaseC also emits n_dst (degree values already in registers -> free norm)
__global__ __launch_bounds__(256) void scan_phaseC(
    const int* __restrict__ deg_in, const int* __restrict__ blocksum,
    int* __restrict__ rowptr, float* __restrict__ n_dst) {
  int r = blockIdx.y, b = blockIdx.x, tid = threadIdx.x;
  const int* deg = deg_in + (size_t)r * NN;
  int* rp = rowptr + (size_t)r * (NN + 1);
  int base = b * 1024 + tid * 4;
  int v[4]; int s = 0;
#pragma unroll
  for (int i = 0; i < 4; ++i) { int idx = base + i; v[i] = (idx < NN) ? deg[idx] : 0; s += v[i]; }
  __shared__ int buf[256];
  buf[tid] = s; __syncthreads();
  for (int off = 1; off < 256; off <<= 1) {
    int t = (tid >= off) ? buf[tid - off] : 0;
    __syncthreads();
    buf[tid] += t;
    __syncthreads();
  }
  int excl = buf[tid] - s + blocksum[r * SCAN_NB + b];
#pragma unroll
  for (int i = 0; i < 4; ++i) {
    int idx = base + i;
    if (idx < NN) {
      rp[idx] = excl;
      n_dst[(size_t)r * NN + idx] = v[i] > 0 ? rsqrtf((float)v[i]) : 0.f;
    }
    excl += v[i];
  }
}

// cursor is a COPY of rowptr (layout [r][NN+1]); atomicAdd gives the absolute
// CSR slot directly. n_src computed on the fly from deg_out (s has an
// out-edge by construction -> deg_out[s] >= 1, no zero guard needed).
__global__ __launch_bounds__(256) void scatter_kernel(
    const int* __restrict__ src, const int* __restrict__ dst,
    int* __restrict__ cursor, const int* __restrict__ deg_out,
    int2* __restrict__ csr_e) {
  int t = blockIdx.x * 256 + threadIdx.x;
  int r = blockIdx.y;
  if (t < NE) {
    int s = src[r * NE + t], v = dst[r * NE + t];
    int pos = atomicAdd(&cursor[r * (NN + 1) + v], 1);   // absolute within relation
    float w = rsqrtf((float)deg_out[r * NN + s]);
    csr_e[(size_t)r * NE + pos] = make_int2(s, __float_as_int(w));
  }
}

// ---------------- weight / feature prep ----------------

// Tiled LDS transpose: W[lay][r][k][n] (f32) -> wt[lay][n][r*256+k] (bf16).
__global__ __launch_bounds__(256) void prep_w_kernel(
    const float* __restrict__ W1, const float* __restrict__ W2,
    unsigned short* __restrict__ wt1, unsigned short* __restrict__ wt2) {
  __shared__ float lds[64][65];
  const int tile = blockIdx.x;          // 0..15: (kt,nt) 4x4
  const int r = blockIdx.y;             // 0..2
  const int lay = blockIdx.z;           // 0..1
  const float* W = lay ? W2 : W1;
  unsigned short* wt = lay ? wt2 : wt1;
  const int k0 = (tile >> 2) * 64, n0 = (tile & 3) * 64;
  const int ty = threadIdx.x >> 6;      // 0..3
  const int tx = threadIdx.x & 63;      // 0..63

#pragma unroll
  for (int i = 0; i < 16; ++i) {
    int kl = ty * 16 + i;               // local k row
    lds[kl][tx] = W[((size_t)r * NF + k0 + kl) * NF + n0 + tx];  // coalesced over tx
  }
  __syncthreads();
#pragma unroll
  for (int i = 0; i < 16; ++i) {
    int nl = ty * 16 + i;               // local n row
    wt[(size_t)(n0 + nl) * NK + r * NF + k0 + tx] = f2bfu(lds[tx][nl]);
  }
}

__global__ __launch_bounds__(256) void prep_bias_kernel(
    const float* __restrict__ b1, const float* __restrict__ b2,
    float* __restrict__ bs1, float* __restrict__ bs2) {
  int t = blockIdx.x * 256 + threadIdx.x;   // 512
  if (t < 2 * NF) {
    int lay = t / NF, n = t % NF;
    const float* b = lay ? b2 : b1;
    float* bs = lay ? bs2 : bs1;
    bs[n] = b[n] + b[NF + n] + b[2 * NF + n];
  }
}

// NT load: feat is read exactly once.
__global__ __launch_bounds__(256) void cast_kernel(
    const float* __restrict__ in, unsigned short* __restrict__ out, int n4) {
  int t = blockIdx.x * 256 + threadIdx.x;
  if (t < n4) {
    floatx4 v = __builtin_nontemporal_load((const floatx4*)&in[(size_t)t * 4]);
    ushortx4 o;
    o.x = f2bfu(v.x); o.y = f2bfu(v.y); o.z = f2bfu(v.z); o.w = f2bfu(v.w);
    *(ushortx4*)&out[(size_t)t * 4] = o;
  }
}

// ---------------- SpMM: one wave per NODE, 3 relations interleaved (R7) ----------------

__global__ __launch_bounds__(256) void spmm_kernel(
    const unsigned short* __restrict__ x,   // [NN][256] bf16
    const int* __restrict__ rowptr, const int2* __restrict__ csr_e,
    const float* __restrict__ n_dst,
    unsigned short* __restrict__ agg) {     // [NN][768] bf16
  int wid = threadIdx.x >> 6, l = threadIdx.x & 63;
  int v = blockIdx.x * 4 + wid;
  if (v >= NN) return;
  const int half = l >> 5;        // 0: edge e, 1: edge e+1
  const int c8 = (l & 31) * 8;    // this lane's 8-col strip

  int ea = rowptr[v],                e1a = rowptr[v + 1];
  int eb = rowptr[(NN + 1) + v],     e1b = rowptr[(NN + 1) + v + 1];
  int ec = rowptr[2 * (NN + 1) + v], e1c = rowptr[2 * (NN + 1) + v + 1];
  const int2* cea = csr_e;
  const int2* ceb = csr_e + (size_t)NE;
  const int2* cec = csr_e + (size_t)2 * NE;

  float a[NR][8];
#pragma unroll
  for (int r = 0; r < NR; ++r)
#pragma unroll
    for (int j = 0; j < 8; ++j) a[r][j] = 0.f;

  while (ea < e1a || eb < e1b || ec < e1c) {
    if (ea < e1a) {
      if (ea + half < e1a) {
        int2 p = cea[ea + half];
        float w = __int_as_float(p.y);
        ushortx8 xv = *(const ushortx8*)&x[(size_t)p.x * NF + c8];
#pragma unroll
        for (int j = 0; j < 8; ++j) a[0][j] += w * bfu2f(xv[j]);
      }
      ea += 2;
    }
    if (eb < e1b) {
      if (eb + half < e1b) {
        int2 p = ceb[eb + half];
        float w = __int_as_float(p.y);
        ushortx8 xv = *(const ushortx8*)&x[(size_t)p.x * NF + c8];
#pragma unroll
        for (int j = 0; j < 8; ++j) a[1][j] += w * bfu2f(xv[j]);
      }
      eb += 2;
    }
    if (ec < e1c) {
      if (ec + half < e1c) {
        int2 p = cec[ec + half];
        float w = __int_as_float(p.y);
        ushortx8 xv = *(const ushortx8*)&x[(size_t)p.x * NF + c8];
#pragma unroll
        for (int j = 0; j < 8; ++j) a[2][j] += w * bfu2f(xv[j]);
      }
      ec += 2;
    }
  }

#pragma unroll
  for (int r = 0; r < NR; ++r)
#pragma unroll
    for (int j = 0; j < 8; ++j) a[r][j] += __shfl_xor(a[r][j], 32);

  if (l < 32) {
#pragma unroll
    for (int r = 0; r < NR; ++r) {
      float nd = n_dst[r * NN + v];
      ushortx8 o;
#pragma unroll
      for (int j = 0; j < 8; ++j) o[j] = f2bfu(a[r][j] * nd);
      *(ushortx8*)&agg[(size_t)v * NK + r * NF + c8] = o;
    }
  }
}

// ---------------- GEMM: [M,768] @ [768,256], BN=256, double-buffered LDS (R11) ----------------

__global__ __launch_bounds__(256, 2) void gemm_kernel(
    const unsigned short* __restrict__ A,    // [M][768] bf16
    const unsigned short* __restrict__ Bt,   // [256][768] bf16 (B^T: [col][K])
    const float* __restrict__ bias,          // [256]
    unsigned short* __restrict__ C,          // [M][256] bf16
    int M, int relu) {
  __shared__ unsigned short ldsA[2][128 * 32];   // [buf][row][32]
  __shared__ unsigned short ldsB[2][256 * 32];   // [buf][col][32]
  const int tid = threadIdx.x;
  const int l = tid & 63, wid = tid >> 6;
  const int row0 = blockIdx.x * 128;
  const int c0 = wid * 64;                    // wave's 64-col strip

  floatx4 acc[8][4];
#pragma unroll
  for (int i = 0; i < 8; ++i)
#pragma unroll
    for (int j = 0; j < 4; ++j)
#pragma unroll
      for (int q = 0; q < 4; ++q) acc[i][j][q] = 0.f;

  const int fr = l & 15, fk = (l >> 4) * 8;

  auto stage = [&](int b, int kt) {
    const int k0 = kt * 32;
    int u = wid * 64 + l;                     // A pass 0: units 0..255
    int arow = row0 + (u >> 2);
    if (arow >= M) arow = M - 1;
    gload16(A + (size_t)arow * NK + k0 + (u & 3) * 8, &ldsA[b][u * 8]);
    u += 256;                                 // A pass 1: units 256..511
    arow = row0 + (u >> 2);
    if (arow >= M) arow = M - 1;
    gload16(A + (size_t)arow * NK + k0 + (u & 3) * 8, &ldsA[b][u * 8]);
#pragma unroll
    for (int p = 0; p < 4; ++p) {             // B: 1024 units
      int uu = p * 256 + wid * 64 + l;
      gload16(Bt + (size_t)(uu >> 2) * NK + k0 + (uu & 3) * 8, &ldsB[b][uu * 8]);
    }
  };

  stage(0, 0);
  asm volatile("s_waitcnt vmcnt(0)" ::: "memory");
  __syncthreads();

  int cur = 0;
  for (int kt = 0; kt < NK / 32; ++kt) {
    if (kt + 1 < NK / 32) stage(cur ^ 1, kt + 1);

    short8 af[8], bf[4];
#pragma unroll
    for (int m = 0; m < 8; ++m)
      af[m] = *(const short8*)&ldsA[cur][(m * 16 + fr) * 32 + fk];
#pragma unroll
    for (int n = 0; n < 4; ++n)
      bf[n] = *(const short8*)&ldsB[cur][(c0 + n * 16 + fr) * 32 + fk];
#pragma unroll
    for (int m = 0; m < 8; ++m)
#pragma unroll
      for (int n = 0; n < 4; ++n)
        acc[m][n] = __builtin_amdgcn_mfma_f32_16x16x32_bf16(af[m], bf[n], acc[m][n], 0, 0, 0);

    asm volatile("s_waitcnt vmcnt(0)" ::: "memory");
    __syncthreads();
    cur ^= 1;
  }

  const int fq = l >> 4;
#pragma unroll
  for (int m = 0; m < 8; ++m) {
#pragma unroll
    for (int n = 0; n < 4; ++n) {
      int col = c0 + n * 16 + fr;
      float bv = bias[col];
#pragma unroll
      for (int q = 0; q < 4; ++q) {
        int row = row0 + m * 16 + fq * 4 + q;
        if (row < M) {
          float vv = acc[m][n][q] + bv;
          if (relu) vv = fmaxf(vv, 0.f);
          C[(size_t)row * NF + col] = f2bfu(vv);
        }
      }
    }
  }
}

// ---------------- pooling ----------------

__global__ __launch_bounds__(256) void pool_kernel(
    const unsigned short* __restrict__ h2, const int* __restrict__ gid,
    float* __restrict__ poolsum) {
  int c = threadIdx.x;                 // column 0..255
  int v0 = blockIdx.x * 256;
  int vend = min(v0 + 256, NN);
  float acc = 0.f;
  int curg = -1;
  for (int v = v0; v < vend; ++v) {
    int g = gid[v];                    // sorted -> few runs per chunk
    if (g != curg) {
      if (curg >= 0) atomicAdd(&poolsum[curg * NF + c], acc);
      curg = g; acc = 0.f;
    }
    acc += bfu2f(h2[(size_t)v * NF + c]);
  }
  if (curg >= 0) atomicAdd(&poolsum[curg * NF + c], acc);
}

// final divides by per-graph count computed via inline binary search on the
// sorted gid (wave-uniform -> scalarized; gid is L2-hot). Replaces gcount_kernel.
__global__ __launch_bounds__(256) void final_kernel(
    const float* __restrict__ poolsum, const int* __restrict__ gid,
    float* __restrict__ out) {
  int g = blockIdx.x, c = threadIdx.x;
  int lo = 0, hi = NN;
  while (lo < hi) { int mid = (lo + hi) >> 1; if (gid[mid] < g) lo = mid + 1; else hi = mid; }
  int a = lo;
  lo = 0; hi = NN;
  while (lo < hi) { int mid = (lo + hi) >> 1; if (gid[mid] < g + 1) lo = mid + 1; else hi = mid; }
  float cnt = (float)(lo - a);
  out[g * NF + c] = poolsum[g * NF + c] / fmaxf(cnt, 1.f);
}

// ---------------- launch ----------------

extern "C" void kernel_launch(void* const* d_in, const int* in_sizes, int n_in,
                              void* d_out, int out_size, void* d_ws, size_t ws_size,
                              hipStream_t stream) {
  const float* feat = (const float*)d_in[0];
  const int* src = (const int*)d_in[1];
  const int* dst = (const int*)d_in[2];
  const int* gid = (const int*)d_in[3];
  const float* W1 = (const float*)d_in[4];
  const float* b1 = (const float*)d_in[5];
  const float* W2 = (const float*)d_in[6];
  const float* b2 = (const float*)d_in[7];
  float* out = (float*)d_out;

  char* ws = (char*)d_ws;
  size_t off = 0;
  auto alloc = [&](size_t bytes) -> void* {
    void* p = ws + off;
    off = (off + bytes + 255) & ~(size_t)255;
    return p;
  };

  // zero-initialized block (single memset)
  int* deg_out = (int*)alloc((size_t)NR * NN * 4);
  int* deg_in  = (int*)alloc((size_t)NR * NN * 4);
  float* poolsum = (float*)alloc((size_t)NG * NF * 4);
  size_t zero_bytes = off;

  int* cursor  = (int*)alloc((size_t)NR * (NN + 1) * 4);
  int* blocksum = (int*)alloc((size_t)NR * SCAN_NB * 4);
  float* n_dst = (float*)alloc((size_t)NR * NN * 4);
  int* rowptr  = (int*)alloc((size_t)NR * (NN + 1) * 4);
  int2* csr_e  = (int2*)alloc((size_t)NR * NE * 8);
  unsigned short* wt1 = (unsigned short*)alloc((size_t)NF * NK * 2);
  unsigned short* wt2 = (unsigned short*)alloc((size_t)NF * NK * 2);
  float* bs1 = (float*)alloc(NF * 4);
  float* bs2 = (float*)alloc(NF * 4);
  unsigned short* featbf = (unsigned short*)alloc((size_t)NN * NF * 2);
  unsigned short* h1 = (unsigned short*)alloc((size_t)NN * NF * 2);
  unsigned short* h2 = (unsigned short*)alloc((size_t)NN * NF * 2);
  unsigned short* agg = (unsigned short*)alloc((size_t)NN * NK * 2);
  (void)ws_size; (void)in_sizes; (void)n_in; (void)out_size;

  hipMemsetAsync(d_ws, 0, zero_bytes, stream);

  dim3 eg((NE + 255) / 256, NR);
  degree_kernel<<<eg, 256, 0, stream>>>(src, dst, deg_out, deg_in);
  scan_phaseA<<<dim3(SCAN_NB, NR), 256, 0, stream>>>(deg_in, blocksum);
  scan_phaseB<<<NR, 128, 0, stream>>>(blocksum, rowptr);
  scan_phaseC<<<dim3(SCAN_NB, NR), 256, 0, stream>>>(deg_in, blocksum, rowptr, n_dst);
  hipMemcpyAsync(cursor, rowptr, (size_t)NR * (NN + 1) * 4,
                 hipMemcpyDeviceToDevice, stream);
  scatter_kernel<<<eg, 256, 0, stream>>>(src, dst, cursor, deg_out, csr_e);

  prep_w_kernel<<<dim3(16, NR, 2), 256, 0, stream>>>(W1, W2, wt1, wt2);
  prep_bias_kernel<<<2, 256, 0, stream>>>(b1, b2, bs1, bs2);
  cast_kernel<<<(NN * NF / 4 + 255) / 256, 256, 0, stream>>>(feat, featbf, NN * NF / 4);

  // layer 1
  spmm_kernel<<<(NN + 3) / 4, 256, 0, stream>>>(featbf, rowptr, csr_e, n_dst, agg);
  gemm_kernel<<<(NN + 127) / 128, 256, 0, stream>>>(agg, wt1, bs1, h1, NN, 1);
  // layer 2
  spmm_kernel<<<(NN + 3) / 4, 256, 0, stream>>>(h1, rowptr, csr_e, n_dst, agg);
  gemm_kernel<<<(NN + 127) / 128, 256, 0, stream>>>(agg, wt2, bs2, h2, NN, 0);
  // pooling
  pool_kernel<<<(NN + 255) / 256, 256, 0, stream>>>(h2, gid, poolsum);
  final_kernel<<<NG, 256, 0, stream>>>(poolsum, gid, out);
}

// Round 14
// 703.214 us; speedup vs baseline: 1.2290x; 1.0291x over previous
//
#include <hip/hip_runtime.h>
#include <stdint.h>

#define NN 100000   // nodes
#define NE 400000   // edges per relation
#define NR 3        // relations
#define NF 256      // feature dim
#define NK 768      // NR*NF concatenated K
#define NG 128      // graphs
#define SCAN_NB ((NN + 1023) / 1024)   // 98 chunks of 1024

typedef __attribute__((ext_vector_type(4))) unsigned short ushortx4;
typedef __attribute__((ext_vector_type(8))) unsigned short ushortx8;
typedef __attribute__((ext_vector_type(8))) short short8;
typedef __attribute__((ext_vector_type(4))) float floatx4;

static __device__ __forceinline__ unsigned short f2bfu(float f) {
  union { float f; uint32_t u; } c; c.f = f;
  uint32_t x = c.u;
  uint32_t r = (x + 0x7fffu + ((x >> 16) & 1u)) >> 16;
  return (unsigned short)r;
}
static __device__ __forceinline__ float bfu2f(unsigned short u) {
  union { uint32_t u; float f; } c; c.u = ((uint32_t)u) << 16;
  return c.f;
}

static __device__ __forceinline__ void gload16(const void* g, void* l) {
  __builtin_amdgcn_global_load_lds(
      (const __attribute__((address_space(1))) uint32_t*)g,
      (__attribute__((address_space(3))) uint32_t*)l, 16, 0, 0);
}

// ---------------- graph preprocessing ----------------

__global__ __launch_bounds__(256) void degree_kernel(
    const int* __restrict__ src, const int* __restrict__ dst,
    int* __restrict__ deg_out, int* __restrict__ deg_in) {
  int t = blockIdx.x * 256 + threadIdx.x;
  int r = blockIdx.y;
  if (t < NE) {
    atomicAdd(&deg_out[r * NN + src[r * NE + t]], 1);
    atomicAdd(&deg_in[r * NN + dst[r * NE + t]], 1);
  }
}

// ---- multi-block exclusive scan of deg_in -> rowptr (3 phases) ----

__global__ __launch_bounds__(256) void scan_phaseA(
    const int* __restrict__ deg_in, int* __restrict__ blocksum) {
  int r = blockIdx.y, b = blockIdx.x, tid = threadIdx.x;
  const int* deg = deg_in + (size_t)r * NN;
  int base = b * 1024 + tid * 4;
  int s = 0;
#pragma unroll
  for (int i = 0; i < 4; ++i) { int idx = base + i; if (idx < NN) s += deg[idx]; }
  __shared__ int red[256];
  red[tid] = s; __syncthreads();
  for (int off = 128; off > 0; off >>= 1) {
    if (tid < off) red[tid] += red[tid + off];
    __syncthreads();
  }
  if (tid == 0) blocksum[r * SCAN_NB + b] = red[0];
}

__global__ __launch_bounds__(128) void scan_phaseB(
    int* __restrict__ blocksum, int* __restrict__ rowptr) {
  int r = blockIdx.x, tid = threadIdx.x;
  int* bs = blocksum + r * SCAN_NB;
  __shared__ int buf[128];
  int v = (tid < SCAN_NB) ? bs[tid] : 0;
  buf[tid] = v; __syncthreads();
  for (int off = 1; off < 128; off <<= 1) {
    int t = (tid >= off) ? buf[tid - off] : 0;
    __syncthreads();
    buf[tid] += t;
    __syncthreads();
  }
  if (tid < SCAN_NB) bs[tid] = buf[tid] - v;   // exclusive chunk offset
  if (tid == 127) rowptr[(size_t)r * (NN + 1) + NN] = buf[127];
}

// phaseC also emits n_dst (degree values already in registers -> free norm)
__global__ __launch_bounds__(256) void scan_phaseC(
    const int* __restrict__ deg_in, const int* __restrict__ blocksum,
    int* __restrict__ rowptr, float* __restrict__ n_dst) {
  int r = blockIdx.y, b = blockIdx.x, tid = threadIdx.x;
  const int* deg = deg_in + (size_t)r * NN;
  int* rp = rowptr + (size_t)r * (NN + 1);
  int base = b * 1024 + tid * 4;
  int v[4]; int s = 0;
#pragma unroll
  for (int i = 0; i < 4; ++i) { int idx = base + i; v[i] = (idx < NN) ? deg[idx] : 0; s += v[i]; }
  __shared__ int buf[256];
  buf[tid] = s; __syncthreads();
  for (int off = 1; off < 256; off <<= 1) {
    int t = (tid >= off) ? buf[tid - off] : 0;
    __syncthreads();
    buf[tid] += t;
    __syncthreads();
  }
  int excl = buf[tid] - s + blocksum[r * SCAN_NB + b];
#pragma unroll
  for (int i = 0; i < 4; ++i) {
    int idx = base + i;
    if (idx < NN) {
      rp[idx] = excl;
      n_dst[(size_t)r * NN + idx] = v[i] > 0 ? rsqrtf((float)v[i]) : 0.f;
    }
    excl += v[i];
  }
}

// cursor is a COPY of rowptr (layout [r][NN+1]); atomicAdd gives the absolute
// CSR slot directly. n_src computed on the fly from deg_out.
__global__ __launch_bounds__(256) void scatter_kernel(
    const int* __restrict__ src, const int* __restrict__ dst,
    int* __restrict__ cursor, const int* __restrict__ deg_out,
    int2* __restrict__ csr_e) {
  int t = blockIdx.x * 256 + threadIdx.x;
  int r = blockIdx.y;
  if (t < NE) {
    int s = src[r * NE + t], v = dst[r * NE + t];
    int pos = atomicAdd(&cursor[r * (NN + 1) + v], 1);   // absolute within relation
    float w = rsqrtf((float)deg_out[r * NN + s]);
    csr_e[(size_t)r * NE + pos] = make_int2(s, __float_as_int(w));
  }
}

// ---------------- weight / feature prep ----------------

// Tiled LDS transpose: W[lay][r][k][n] (f32) -> wt[lay][n][r*256+k] (bf16).
__global__ __launch_bounds__(256) void prep_w_kernel(
    const float* __restrict__ W1, const float* __restrict__ W2,
    unsigned short* __restrict__ wt1, unsigned short* __restrict__ wt2) {
  __shared__ float lds[64][65];
  const int tile = blockIdx.x;          // 0..15: (kt,nt) 4x4
  const int r = blockIdx.y;             // 0..2
  const int lay = blockIdx.z;           // 0..1
  const float* W = lay ? W2 : W1;
  unsigned short* wt = lay ? wt2 : wt1;
  const int k0 = (tile >> 2) * 64, n0 = (tile & 3) * 64;
  const int ty = threadIdx.x >> 6;      // 0..3
  const int tx = threadIdx.x & 63;      // 0..63

#pragma unroll
  for (int i = 0; i < 16; ++i) {
    int kl = ty * 16 + i;               // local k row
    lds[kl][tx] = W[((size_t)r * NF + k0 + kl) * NF + n0 + tx];  // coalesced over tx
  }
  __syncthreads();
#pragma unroll
  for (int i = 0; i < 16; ++i) {
    int nl = ty * 16 + i;               // local n row
    wt[(size_t)(n0 + nl) * NK + r * NF + k0 + tx] = f2bfu(lds[tx][nl]);
  }
}

__global__ __launch_bounds__(256) void prep_bias_kernel(
    const float* __restrict__ b1, const float* __restrict__ b2,
    float* __restrict__ bs1, float* __restrict__ bs2) {
  int t = blockIdx.x * 256 + threadIdx.x;   // 512
  if (t < 2 * NF) {
    int lay = t / NF, n = t % NF;
    const float* b = lay ? b2 : b1;
    float* bs = lay ? bs2 : bs1;
    bs[n] = b[n] + b[NF + n] + b[2 * NF + n];
  }
}

// NT load: feat is read exactly once.
__global__ __launch_bounds__(256) void cast_kernel(
    const float* __restrict__ in, unsigned short* __restrict__ out, int n4) {
  int t = blockIdx.x * 256 + threadIdx.x;
  if (t < n4) {
    floatx4 v = __builtin_nontemporal_load((const floatx4*)&in[(size_t)t * 4]);
    ushortx4 o;
    o.x = f2bfu(v.x); o.y = f2bfu(v.y); o.z = f2bfu(v.z); o.w = f2bfu(v.w);
    *(ushortx4*)&out[(size_t)t * 4] = o;
  }
}

// ---------------- SpMM: one wave per NODE, 3 relations interleaved ----------------
// csr-entry PREFETCH: next pair's int2 loads issue concurrently with the current
// gathers, breaking the serial csr->gather dependent chain.

__global__ __launch_bounds__(256) void spmm_kernel(
    const unsigned short* __restrict__ x,   // [NN][256] bf16
    const int* __restrict__ rowptr, const int2* __restrict__ csr_e,
    const float* __restrict__ n_dst,
    unsigned short* __restrict__ agg) {     // [NN][768] bf16
  int wid = threadIdx.x >> 6, l = threadIdx.x & 63;
  int v = blockIdx.x * 4 + wid;
  if (v >= NN) return;
  const int half = l >> 5;        // 0: edge e, 1: edge e+1
  const int c8 = (l & 31) * 8;    // this lane's 8-col strip

  int ea = rowptr[v],                e1a = rowptr[v + 1];
  int eb = rowptr[(NN + 1) + v],     e1b = rowptr[(NN + 1) + v + 1];
  int ec = rowptr[2 * (NN + 1) + v], e1c = rowptr[2 * (NN + 1) + v + 1];
  const int2* cea = csr_e;
  const int2* ceb = csr_e + (size_t)NE;
  const int2* cec = csr_e + (size_t)2 * NE;

  float a[NR][8];
#pragma unroll
  for (int r = 0; r < NR; ++r)
#pragma unroll
    for (int j = 0; j < 8; ++j) a[r][j] = 0.f;

  int2 qa = make_int2(0, 0), qb = make_int2(0, 0), qc = make_int2(0, 0);
  if (ea + half < e1a) qa = cea[ea + half];
  if (eb + half < e1b) qb = ceb[eb + half];
  if (ec + half < e1c) qc = cec[ec + half];

  while (ea < e1a || eb < e1b || ec < e1c) {
    int2 na = make_int2(0, 0), nb = make_int2(0, 0), nc = make_int2(0, 0);
    if (ea + 2 + half < e1a) na = cea[ea + 2 + half];
    if (eb + 2 + half < e1b) nb = ceb[eb + 2 + half];
    if (ec + 2 + half < e1c) nc = cec[ec + 2 + half];

    if (ea < e1a) {
      if (ea + half < e1a) {
        float w = __int_as_float(qa.y);
        ushortx8 xv = *(const ushortx8*)&x[(size_t)qa.x * NF + c8];
#pragma unroll
        for (int j = 0; j < 8; ++j) a[0][j] += w * bfu2f(xv[j]);
      }
      ea += 2; qa = na;
    }
    if (eb < e1b) {
      if (eb + half < e1b) {
        float w = __int_as_float(qb.y);
        ushortx8 xv = *(const ushortx8*)&x[(size_t)qb.x * NF + c8];
#pragma unroll
        for (int j = 0; j < 8; ++j) a[1][j] += w * bfu2f(xv[j]);
      }
      eb += 2; qb = nb;
    }
    if (ec < e1c) {
      if (ec + half < e1c) {
        float w = __int_as_float(qc.y);
        ushortx8 xv = *(const ushortx8*)&x[(size_t)qc.x * NF + c8];
#pragma unroll
        for (int j = 0; j < 8; ++j) a[2][j] += w * bfu2f(xv[j]);
      }
      ec += 2; qc = nc;
    }
  }

#pragma unroll
  for (int r = 0; r < NR; ++r)
#pragma unroll
    for (int j = 0; j < 8; ++j) a[r][j] += __shfl_xor(a[r][j], 32);

  if (l < 32) {
#pragma unroll
    for (int r = 0; r < NR; ++r) {
      float nd = n_dst[r * NN + v];
      ushortx8 o;
#pragma unroll
      for (int j = 0; j < 8; ++j) o[j] = f2bfu(a[r][j] * nd);
      *(ushortx8*)&agg[(size_t)v * NK + r * NF + c8] = o;
    }
  }
}

// ---------------- GEMM: [M,768] @ [768,256], counted-vmcnt 2-deep pipeline ----------------
// A 3-buffered (staged 2 K-steps ahead, hides L3 latency of agg reads);
// B 2-buffered (1 ahead, L2-hot). ONE raw s_barrier per K-step, s_waitcnt
// vmcnt(2) (never 0 until the last step) -- T3/T4 recipe. LDS 56KB.
// Safety: each buffer overwritten at iter kt was last read at iter kt-1,
// ordered by iter kt's barrier.

__global__ __launch_bounds__(256, 2) void gemm_kernel(
    const unsigned short* __restrict__ A,    // [M][768] bf16
    const unsigned short* __restrict__ Bt,   // [256][768] bf16 (B^T: [col][K])
    const float* __restrict__ bias,          // [256]
    unsigned short* __restrict__ C,          // [M][256] bf16
    int M, int relu) {
  __shared__ unsigned short ldsA[3][128 * 32];   // 24KB
  __shared__ unsigned short ldsB[2][256 * 32];   // 32KB
  const int tid = threadIdx.x;
  const int l = tid & 63, wid = tid >> 6;
  const int row0 = blockIdx.x * 128;
  const int c0 = wid * 64;                    // wave's 64-col strip

  floatx4 acc[8][4];
#pragma unroll
  for (int i = 0; i < 8; ++i)
#pragma unroll
    for (int j = 0; j < 4; ++j)
#pragma unroll
      for (int q = 0; q < 4; ++q) acc[i][j][q] = 0.f;

  const int fr = l & 15, fk = (l >> 4) * 8;

  auto stageA = [&](int b, int kt) {
    const int k0 = kt * 32;
    int u = wid * 64 + l;                     // units 0..255
    int arow = row0 + (u >> 2);
    if (arow >= M) arow = M - 1;
    gload16(A + (size_t)arow * NK + k0 + (u & 3) * 8, &ldsA[b][u * 8]);
    u += 256;                                 // units 256..511
    arow = row0 + (u >> 2);
    if (arow >= M) arow = M - 1;
    gload16(A + (size_t)arow * NK + k0 + (u & 3) * 8, &ldsA[b][u * 8]);
  };
  auto stageB = [&](int b, int kt) {
    const int k0 = kt * 32;
#pragma unroll
    for (int p = 0; p < 4; ++p) {             // 1024 units
      int uu = p * 256 + wid * 64 + l;
      gload16(Bt + (size_t)(uu >> 2) * NK + k0 + (uu & 3) * 8, &ldsB[b][uu * 8]);
    }
  };

  const int NKT = NK / 32;                    // 24
  // prologue: B(0) [4 loads], A(0) [2], A(1) [2]  -> 8 outstanding
  stageB(0, 0);
  stageA(0, 0);
  stageA(1, 1);

  for (int kt = 0; kt < NKT; ++kt) {
    // in-flight (oldest->newest) at this point: A(kt) [iter kt-2],
    // B(kt) [iter kt-1], A(kt+1) [iter kt-1]. vmcnt(2) leaves only A(kt+1).
    if (kt < NKT - 1) {
      asm volatile("s_waitcnt vmcnt(2)" ::: "memory");
    } else {
      asm volatile("s_waitcnt vmcnt(0)" ::: "memory");
    }
    __builtin_amdgcn_s_barrier();
    __builtin_amdgcn_sched_barrier(0);

    if (kt + 1 < NKT) stageB((kt + 1) & 1, kt + 1);
    if (kt + 2 < NKT) stageA((kt + 2) % 3, kt + 2);
    __builtin_amdgcn_sched_barrier(0);

    const int ba = kt % 3, bb = kt & 1;
    short8 af[8], bf[4];
#pragma unroll
    for (int m = 0; m < 8; ++m)
      af[m] = *(const short8*)&ldsA[ba][(m * 16 + fr) * 32 + fk];
#pragma unroll
    for (int n = 0; n < 4; ++n)
      bf[n] = *(const short8*)&ldsB[bb][(c0 + n * 16 + fr) * 32 + fk];
#pragma unroll
    for (int m = 0; m < 8; ++m)
#pragma unroll
      for (int n = 0; n < 4; ++n)
        acc[m][n] = __builtin_amdgcn_mfma_f32_16x16x32_bf16(af[m], bf[n], acc[m][n], 0, 0, 0);
  }

  const int fq = l >> 4;
#pragma unroll
  for (int m = 0; m < 8; ++m) {
#pragma unroll
    for (int n = 0; n < 4; ++n) {
      int col = c0 + n * 16 + fr;
      float bv = bias[col];
#pragma unroll
      for (int q = 0; q < 4; ++q) {
        int row = row0 + m * 16 + fq * 4 + q;
        if (row < M) {
          float vv = acc[m][n][q] + bv;
          if (relu) vv = fmaxf(vv, 0.f);
          C[(size_t)row * NF + col] = f2bfu(vv);
        }
      }
    }
  }
}

// ---------------- pooling ----------------

__global__ __launch_bounds__(256) void pool_kernel(
    const unsigned short* __restrict__ h2, const int* __restrict__ gid,
    float* __restrict__ poolsum) {
  int c = threadIdx.x;                 // column 0..255
  int v0 = blockIdx.x * 256;
  int vend = min(v0 + 256, NN);
  float acc = 0.f;
  int curg = -1;
  for (int v = v0; v < vend; ++v) {
    int g = gid[v];                    // sorted -> few runs per chunk
    if (g != curg) {
      if (curg >= 0) atomicAdd(&poolsum[curg * NF + c], acc);
      curg = g; acc = 0.f;
    }
    acc += bfu2f(h2[(size_t)v * NF + c]);
  }
  if (curg >= 0) atomicAdd(&poolsum[curg * NF + c], acc);
}

// final divides by per-graph count via inline binary search on sorted gid.
__global__ __launch_bounds__(256) void final_kernel(
    const float* __restrict__ poolsum, const int* __restrict__ gid,
    float* __restrict__ out) {
  int g = blockIdx.x, c = threadIdx.x;
  int lo = 0, hi = NN;
  while (lo < hi) { int mid = (lo + hi) >> 1; if (gid[mid] < g) lo = mid + 1; else hi = mid; }
  int a = lo;
  lo = 0; hi = NN;
  while (lo < hi) { int mid = (lo + hi) >> 1; if (gid[mid] < g + 1) lo = mid + 1; else hi = mid; }
  float cnt = (float)(lo - a);
  out[g * NF + c] = poolsum[g * NF + c] / fmaxf(cnt, 1.f);
}

// ---------------- launch ----------------

extern "C" void kernel_launch(void* const* d_in, const int* in_sizes, int n_in,
                              void* d_out, int out_size, void* d_ws, size_t ws_size,
                              hipStream_t stream) {
  const float* feat = (const float*)d_in[0];
  const int* src = (const int*)d_in[1];
  const int* dst = (const int*)d_in[2];
  const int* gid = (const int*)d_in[3];
  const float* W1 = (const float*)d_in[4];
  const float* b1 = (const float*)d_in[5];
  const float* W2 = (const float*)d_in[6];
  const float* b2 = (const float*)d_in[7];
  float* out = (float*)d_out;

  char* ws = (char*)d_ws;
  size_t off = 0;
  auto alloc = [&](size_t bytes) -> void* {
    void* p = ws + off;
    off = (off + bytes + 255) & ~(size_t)255;
    return p;
  };

  // zero-initialized block (single memset)
  int* deg_out = (int*)alloc((size_t)NR * NN * 4);
  int* deg_in  = (int*)alloc((size_t)NR * NN * 4);
  float* poolsum = (float*)alloc((size_t)NG * NF * 4);
  size_t zero_bytes = off;

  int* cursor  = (int*)alloc((size_t)NR * (NN + 1) * 4);
  int* blocksum = (int*)alloc((size_t)NR * SCAN_NB * 4);
  float* n_dst = (float*)alloc((size_t)NR * NN * 4);
  int* rowptr  = (int*)alloc((size_t)NR * (NN + 1) * 4);
  int2* csr_e  = (int2*)alloc((size_t)NR * NE * 8);
  unsigned short* wt1 = (unsigned short*)alloc((size_t)NF * NK * 2);
  unsigned short* wt2 = (unsigned short*)alloc((size_t)NF * NK * 2);
  float* bs1 = (float*)alloc(NF * 4);
  float* bs2 = (float*)alloc(NF * 4);
  unsigned short* featbf = (unsigned short*)alloc((size_t)NN * NF * 2);
  unsigned short* h1 = (unsigned short*)alloc((size_t)NN * NF * 2);
  unsigned short* h2 = (unsigned short*)alloc((size_t)NN * NF * 2);
  unsigned short* agg = (unsigned short*)alloc((size_t)NN * NK * 2);
  (void)ws_size; (void)in_sizes; (void)n_in; (void)out_size;

  hipMemsetAsync(d_ws, 0, zero_bytes, stream);

  dim3 eg((NE + 255) / 256, NR);
  degree_kernel<<<eg, 256, 0, stream>>>(src, dst, deg_out, deg_in);
  scan_phaseA<<<dim3(SCAN_NB, NR), 256, 0, stream>>>(deg_in, blocksum);
  scan_phaseB<<<NR, 128, 0, stream>>>(blocksum, rowptr);
  scan_phaseC<<<dim3(SCAN_NB, NR), 256, 0, stream>>>(deg_in, blocksum, rowptr, n_dst);
  hipMemcpyAsync(cursor, rowptr, (size_t)NR * (NN + 1) * 4,
                 hipMemcpyDeviceToDevice, stream);
  scatter_kernel<<<eg, 256, 0, stream>>>(src, dst, cursor, deg_out, csr_e);

  prep_w_kernel<<<dim3(16, NR, 2), 256, 0, stream>>>(W1, W2, wt1, wt2);
  prep_bias_kernel<<<2, 256, 0, stream>>>(b1, b2, bs1, bs2);
  cast_kernel<<<(NN * NF / 4 + 255) / 256, 256, 0, stream>>>(feat, featbf, NN * NF / 4);

  // layer 1
  spmm_kernel<<<(NN + 3) / 4, 256, 0, stream>>>(featbf, rowptr, csr_e, n_dst, agg);
  gemm_kernel<<<(NN + 127) / 128, 256, 0, stream>>>(agg, wt1, bs1, h1, NN, 1);
  // layer 2
  spmm_kernel<<<(NN + 3) / 4, 256, 0, stream>>>(h1, rowptr, csr_e, n_dst, agg);
  gemm_kernel<<<(NN + 127) / 128, 256, 0, stream>>>(agg, wt2, bs2, h2, NN, 0);
  // pooling
  pool_kernel<<<(NN + 255) / 256, 256, 0, stream>>>(h2, gid, poolsum);
  final_kernel<<<NG, 256, 0, stream>>>(poolsum, gid, out);
}